// Round 1
// baseline (558.238 us; speedup 1.0000x reference)
//
#include <hip/hip_runtime.h>

typedef __attribute__((ext_vector_type(8))) short bf16x8;
typedef __attribute__((ext_vector_type(4))) float f32x4;

#define B_ 8
#define H_ 8
#define N_ 2048
#define D_ 384
#define E_ 1152
#define M_ (B_ * N_)
#define DK_ 48
#define DKP_ 64

__device__ __forceinline__ unsigned short f2bf(float f) {
  unsigned int u = __builtin_bit_cast(unsigned int, f);
  u = u + 0x7fffu + ((u >> 16) & 1u);
  return (unsigned short)(u >> 16);
}

// ---------------- kernel 1: casts + weight transposes ----------------
__global__ __launch_bounds__(256) void cast_kernel(
    const float* __restrict__ x, const float* __restrict__ Wqkv,
    const float* __restrict__ Wo, unsigned short* __restrict__ xb,
    unsigned short* __restrict__ WtQ, unsigned short* __restrict__ WtO) {
  const int NX4 = M_ * D_ / 4;   // 1572864
  const int NW1 = D_ * E_;       // 442368
  const int NW2 = D_ * D_;       // 147456
  int i = blockIdx.x * 256 + threadIdx.x;
  if (i < NX4) {
    float4 v = ((const float4*)x)[i];
    ushort4 o;
    o.x = f2bf(v.x); o.y = f2bf(v.y); o.z = f2bf(v.z); o.w = f2bf(v.w);
    ((ushort4*)xb)[i] = o;
  } else if (i < NX4 + NW1) {
    int j = i - NX4;
    int k = j / E_, e = j - k * E_;
    WtQ[e * D_ + k] = f2bf(Wqkv[j]);   // W_qkv^T : [1152][384]
  } else if (i < NX4 + NW1 + NW2) {
    int j = i - NX4 - NW1;
    int k = j / D_, e = j - k * D_;
    WtO[e * D_ + k] = f2bf(Wo[j]);     // W_o^T : [384][384]
  }
}

// ---------------- kernel 2: QKV GEMM + head scatter ----------------
// C[M,1152] = xb[M,384] @ Wqkv[384,1152]; scatter into Q/K padded [bh][n][64], Vt [bh][48][n]
__global__ __launch_bounds__(256) void gemm_qkv(
    const unsigned short* __restrict__ Xb, const unsigned short* __restrict__ Wt,
    unsigned short* __restrict__ Qo, unsigned short* __restrict__ Ko,
    unsigned short* __restrict__ Vto) {
  __shared__ unsigned short Als[128 * 32];
  __shared__ unsigned short Bls[128 * 32];
  int t = threadIdx.x;
  int w = t >> 6, lane = t & 63, lo = lane & 15, hi = lane >> 4;
  int wr = w >> 1, wc = w & 1;
  int m0 = blockIdx.y * 128, n0 = blockIdx.x * 128;
  f32x4 acc[4][4] = {};
  for (int k0 = 0; k0 < D_; k0 += 32) {
#pragma unroll
    for (int it = 0; it < 2; ++it) {
      int o = it * 4096 + t * 16;           // byte offset in 8KB tile
      int row = o >> 6, colb = o & 63;
      *(bf16x8*)((char*)Als + o) =
          *(const bf16x8*)((const char*)Xb + (size_t)(m0 + row) * 768 + (size_t)k0 * 2 + colb);
      *(bf16x8*)((char*)Bls + o) =
          *(const bf16x8*)((const char*)Wt + (size_t)(n0 + row) * 768 + (size_t)k0 * 2 + colb);
    }
    __syncthreads();
    bf16x8 a[4], b[4];
#pragma unroll
    for (int m = 0; m < 4; ++m)
      a[m] = *(const bf16x8*)((const char*)Als + (wr * 64 + m * 16 + lo) * 64 + hi * 16);
#pragma unroll
    for (int n = 0; n < 4; ++n)
      b[n] = *(const bf16x8*)((const char*)Bls + (wc * 64 + n * 16 + lo) * 64 + hi * 16);
#pragma unroll
    for (int m = 0; m < 4; ++m)
#pragma unroll
      for (int n = 0; n < 4; ++n)
        acc[m][n] = __builtin_amdgcn_mfma_f32_16x16x32_bf16(a[m], b[n], acc[m][n], 0, 0, 0);
    __syncthreads();
  }
  // epilogue scatter
#pragma unroll
  for (int m = 0; m < 4; ++m)
#pragma unroll
    for (int n = 0; n < 4; ++n)
#pragma unroll
      for (int r = 0; r < 4; ++r) {
        int row = m0 + wr * 64 + m * 16 + 4 * hi + r;   // token index in [0,16384)
        int col = n0 + wc * 64 + n * 16 + lo;           // e in [0,1152)
        unsigned short bv = f2bf(acc[m][n][r]);
        int bb = row >> 11, nn = row & 2047;
        int tsel = col / 384;
        int rr = col - tsel * 384;
        int hh = rr / 48, dd = rr - hh * 48;
        size_t bh = (size_t)(bb * 8 + hh);
        if (tsel == 0)
          Qo[bh * N_ * DKP_ + (size_t)nn * DKP_ + dd] = bv;
        else if (tsel == 1)
          Ko[bh * N_ * DKP_ + (size_t)nn * DKP_ + dd] = bv;
        else
          Vto[bh * DK_ * N_ + (size_t)dd * N_ + nn] = bv;
      }
}

// ---------------- kernel 3: flash attention ----------------
// grid (32 qtiles, 64 bh), 256 threads = 4 waves, each wave owns 16 q-rows
__global__ __launch_bounds__(256) void attn_kernel(
    const unsigned short* __restrict__ Q, const unsigned short* __restrict__ K,
    const unsigned short* __restrict__ Vt, unsigned short* __restrict__ AO) {
  __shared__ unsigned short plds[4][16][72];   // per-wave P buffer, padded stride 144B
  int qt = blockIdx.x, bh = blockIdx.y;
  int t = threadIdx.x, w = t >> 6, lane = t & 63, lo = lane & 15, hi = lane >> 4;
  const unsigned short* Qb = Q + (size_t)bh * N_ * DKP_;
  const unsigned short* Kb = K + (size_t)bh * N_ * DKP_;
  const unsigned short* Vb = Vt + (size_t)bh * DK_ * N_;
  int qrow0 = qt * 64 + w * 16;
  const float SCALE = 0.02209708691207961f;        // 1/sqrt(2048)
  const float LOG2E = 1.4426950408889634f;

  bf16x8 aq[2];
#pragma unroll
  for (int kk = 0; kk < 2; ++kk)
    aq[kk] = *(const bf16x8*)(Qb + (size_t)(qrow0 + lo) * DKP_ + kk * 32 + hi * 8);

  f32x4 o[3] = {};
  float m[4] = {-1e30f, -1e30f, -1e30f, -1e30f};
  float lsum[4] = {0.f, 0.f, 0.f, 0.f};

  for (int kv0 = 0; kv0 < N_; kv0 += 64) {
    f32x4 s[4] = {};
#pragma unroll
    for (int c = 0; c < 4; ++c)
#pragma unroll
      for (int kk = 0; kk < 2; ++kk) {
        bf16x8 bk = *(const bf16x8*)(Kb + (size_t)(kv0 + c * 16 + lo) * DKP_ + kk * 32 + hi * 8);
        s[c] = __builtin_amdgcn_mfma_f32_16x16x32_bf16(aq[kk], bk, s[c], 0, 0, 0);
      }
    float mnew[4], corr[4];
#pragma unroll
    for (int r = 0; r < 4; ++r) {
      float mx = fmaxf(fmaxf(s[0][r], s[1][r]), fmaxf(s[2][r], s[3][r])) * SCALE;
#pragma unroll
      for (int d = 1; d < 16; d <<= 1) mx = fmaxf(mx, __shfl_xor(mx, d));
      mnew[r] = fmaxf(m[r], mx);
      corr[r] = exp2f((m[r] - mnew[r]) * LOG2E);
      m[r] = mnew[r];
    }
    float rs[4] = {0.f, 0.f, 0.f, 0.f};
#pragma unroll
    for (int c = 0; c < 4; ++c)
#pragma unroll
      for (int r = 0; r < 4; ++r) {
        float pv = exp2f((s[c][r] * SCALE - mnew[r]) * LOG2E);
        plds[w][4 * hi + r][c * 16 + lo] = f2bf(pv);
        rs[r] += pv;
      }
#pragma unroll
    for (int r = 0; r < 4; ++r) {
      float v = rs[r];
#pragma unroll
      for (int d = 1; d < 16; d <<= 1) v += __shfl_xor(v, d);
      lsum[r] = lsum[r] * corr[r] + v;
      o[0][r] *= corr[r];
      o[1][r] *= corr[r];
      o[2][r] *= corr[r];
    }
    asm volatile("s_waitcnt lgkmcnt(0)" ::: "memory");
    bf16x8 ap[2];
#pragma unroll
    for (int kk = 0; kk < 2; ++kk)
      ap[kk] = *(const bf16x8*)((const char*)&plds[w][lo][0] + kk * 64 + hi * 16);
#pragma unroll
    for (int c3 = 0; c3 < 3; ++c3)
#pragma unroll
      for (int kk = 0; kk < 2; ++kk) {
        bf16x8 bv = *(const bf16x8*)(Vb + (size_t)(c3 * 16 + lo) * N_ + kv0 + kk * 32 + hi * 8);
        o[c3] = __builtin_amdgcn_mfma_f32_16x16x32_bf16(ap[kk], bv, o[c3], 0, 0, 0);
      }
  }
  int bb = bh >> 3, hh = bh & 7;
#pragma unroll
  for (int c3 = 0; c3 < 3; ++c3)
#pragma unroll
    for (int r = 0; r < 4; ++r) {
      int n = qrow0 + 4 * hi + r;
      AO[(size_t)(bb * N_ + n) * D_ + hh * DK_ + c3 * 16 + lo] = f2bf(o[c3][r] / lsum[r]);
    }
}

// ---------------- kernel 4: output projection + bias ----------------
__global__ __launch_bounds__(256) void gemm_out(
    const unsigned short* __restrict__ Ab, const unsigned short* __restrict__ Wt,
    const float* __restrict__ bias, float* __restrict__ Out) {
  __shared__ unsigned short Als[128 * 32];
  __shared__ unsigned short Bls[128 * 32];
  int t = threadIdx.x;
  int w = t >> 6, lane = t & 63, lo = lane & 15, hi = lane >> 4;
  int wr = w >> 1, wc = w & 1;
  int m0 = blockIdx.y * 128, n0 = blockIdx.x * 128;
  f32x4 acc[4][4] = {};
  for (int k0 = 0; k0 < D_; k0 += 32) {
#pragma unroll
    for (int it = 0; it < 2; ++it) {
      int o = it * 4096 + t * 16;
      int row = o >> 6, colb = o & 63;
      *(bf16x8*)((char*)Als + o) =
          *(const bf16x8*)((const char*)Ab + (size_t)(m0 + row) * 768 + (size_t)k0 * 2 + colb);
      *(bf16x8*)((char*)Bls + o) =
          *(const bf16x8*)((const char*)Wt + (size_t)(n0 + row) * 768 + (size_t)k0 * 2 + colb);
    }
    __syncthreads();
    bf16x8 a[4], b[4];
#pragma unroll
    for (int m = 0; m < 4; ++m)
      a[m] = *(const bf16x8*)((const char*)Als + (wr * 64 + m * 16 + lo) * 64 + hi * 16);
#pragma unroll
    for (int n = 0; n < 4; ++n)
      b[n] = *(const bf16x8*)((const char*)Bls + (wc * 64 + n * 16 + lo) * 64 + hi * 16);
#pragma unroll
    for (int m = 0; m < 4; ++m)
#pragma unroll
      for (int n = 0; n < 4; ++n)
        acc[m][n] = __builtin_amdgcn_mfma_f32_16x16x32_bf16(a[m], b[n], acc[m][n], 0, 0, 0);
    __syncthreads();
  }
  float bvals[4];
#pragma unroll
  for (int n = 0; n < 4; ++n) bvals[n] = bias[n0 + wc * 64 + n * 16 + lo];
#pragma unroll
  for (int m = 0; m < 4; ++m)
#pragma unroll
    for (int n = 0; n < 4; ++n)
#pragma unroll
      for (int r = 0; r < 4; ++r) {
        int row = m0 + wr * 64 + m * 16 + 4 * hi + r;
        int col = n0 + wc * 64 + n * 16 + lo;
        Out[(size_t)row * D_ + col] = acc[m][n][r] + bvals[n];
      }
}

extern "C" void kernel_launch(void* const* d_in, const int* in_sizes, int n_in,
                              void* d_out, int out_size, void* d_ws, size_t ws_size,
                              hipStream_t stream) {
  const float* x    = (const float*)d_in[0];
  const float* Wqkv = (const float*)d_in[1];
  const float* Wo   = (const float*)d_in[2];
  const float* bo   = (const float*)d_in[3];
  float* out = (float*)d_out;
  char* ws = (char*)d_ws;

  // workspace layout (bytes)
  unsigned short* xb  = (unsigned short*)(ws);               // 12,582,912
  unsigned short* WtQ = (unsigned short*)(ws + 12582912);    //    884,736
  unsigned short* WtO = (unsigned short*)(ws + 13467648);    //    294,912
  unsigned short* Qp  = (unsigned short*)(ws + 13762560);    // 16,777,216
  unsigned short* Kp  = (unsigned short*)(ws + 30539776);    // 16,777,216
  unsigned short* Vt  = (unsigned short*)(ws + 47316992);    // 12,582,912
  unsigned short* AO  = (unsigned short*)(ws + 59899904);    // 12,582,912
  const size_t WS_NEED = 72482816;
  if (ws_size < WS_NEED) return;  // visible failure instead of corruption

  hipMemsetAsync(Qp, 0, (size_t)16777216, stream);  // zero dk-pad 48..63
  hipMemsetAsync(Kp, 0, (size_t)16777216, stream);
  cast_kernel<<<8448, 256, 0, stream>>>(x, Wqkv, Wo, xb, WtQ, WtO);
  gemm_qkv<<<dim3(9, 128), 256, 0, stream>>>(xb, WtQ, Qp, Kp, Vt);
  attn_kernel<<<dim3(32, 64), 256, 0, stream>>>(Qp, Kp, Vt, AO);
  gemm_out<<<dim3(3, 128), 256, 0, stream>>>(AO, WtO, bo, out);
}

// Round 2
// 306.025 us; speedup vs baseline: 1.8242x; 1.8242x over previous
//
#include <hip/hip_runtime.h>

typedef __attribute__((ext_vector_type(8))) short bf16x8;
typedef __attribute__((ext_vector_type(4))) float f32x4;
typedef __attribute__((ext_vector_type(16))) float f32x16;
typedef __attribute__((ext_vector_type(4))) unsigned u32x4;

#define B_ 8
#define H_ 8
#define N_ 2048
#define D_ 384
#define E_ 1152
#define M_ (B_ * N_)
#define DK_ 48

__device__ __forceinline__ unsigned short f2bf(float f) {
  unsigned int u = __builtin_bit_cast(unsigned int, f);
  u = u + 0x7fffu + ((u >> 16) & 1u);
  return (unsigned short)(u >> 16);
}

__device__ __forceinline__ unsigned cvt_pk_bf16(float lo, float hi) {
  unsigned r;
  asm("v_cvt_pk_bf16_f32 %0, %1, %2" : "=v"(r) : "v"(lo), "v"(hi));
  return r;
}

__device__ __forceinline__ float tmax16(const f32x16& v) {
  float a0 = fmaxf(v[0], v[1]), a1 = fmaxf(v[2], v[3]);
  float a2 = fmaxf(v[4], v[5]), a3 = fmaxf(v[6], v[7]);
  float a4 = fmaxf(v[8], v[9]), a5 = fmaxf(v[10], v[11]);
  float a6 = fmaxf(v[12], v[13]), a7 = fmaxf(v[14], v[15]);
  float b0 = fmaxf(a0, a1), b1 = fmaxf(a2, a3), b2 = fmaxf(a4, a5), b3 = fmaxf(a6, a7);
  return fmaxf(fmaxf(b0, b1), fmaxf(b2, b3));
}

__device__ __forceinline__ float tsum16(const f32x16& v) {
  float a0 = v[0] + v[1], a1 = v[2] + v[3], a2 = v[4] + v[5], a3 = v[6] + v[7];
  float a4 = v[8] + v[9], a5 = v[10] + v[11], a6 = v[12] + v[13], a7 = v[14] + v[15];
  float b0 = a0 + a1, b1 = a2 + a3, b2 = a4 + a5, b3 = a6 + a7;
  return (b0 + b1) + (b2 + b3);
}

// ---------------- kernel 1: casts + weight transposes ----------------
__global__ __launch_bounds__(256) void cast_kernel(
    const float* __restrict__ x, const float* __restrict__ Wqkv,
    const float* __restrict__ Wo, unsigned short* __restrict__ xb,
    unsigned short* __restrict__ WtQ, unsigned short* __restrict__ WtO) {
  const int NX4 = M_ * D_ / 4;
  const int NW1 = D_ * E_;
  const int NW2 = D_ * D_;
  int i = blockIdx.x * 256 + threadIdx.x;
  if (i < NX4) {
    float4 v = ((const float4*)x)[i];
    ushort4 o;
    o.x = f2bf(v.x); o.y = f2bf(v.y); o.z = f2bf(v.z); o.w = f2bf(v.w);
    ((ushort4*)xb)[i] = o;
  } else if (i < NX4 + NW1) {
    int j = i - NX4;
    int k = j / E_, e = j - k * E_;
    WtQ[e * D_ + k] = f2bf(Wqkv[j]);   // W_qkv^T : [1152][384]
  } else if (i < NX4 + NW1 + NW2) {
    int j = i - NX4 - NW1;
    int k = j / D_, e = j - k * D_;
    WtO[e * D_ + k] = f2bf(Wo[j]);     // W_o^T : [384][384]
  }
}

// ---------------- kernel 2: QKV GEMM + head scatter ----------------
// Q,K -> [bh][n][48] ; V -> V^T [bh][64][n] (rows 48..63 left unwritten)
__global__ __launch_bounds__(256) void gemm_qkv(
    const unsigned short* __restrict__ Xb, const unsigned short* __restrict__ Wt,
    unsigned short* __restrict__ Qo, unsigned short* __restrict__ Ko,
    unsigned short* __restrict__ Vto) {
  __shared__ unsigned short Als[128 * 32];
  __shared__ unsigned short Bls[128 * 32];
  int t = threadIdx.x;
  int w = t >> 6, lane = t & 63, lo = lane & 15, hi = lane >> 4;
  int wr = w >> 1, wc = w & 1;
  int m0 = blockIdx.y * 128, n0 = blockIdx.x * 128;
  f32x4 acc[4][4] = {};
  for (int k0 = 0; k0 < D_; k0 += 32) {
#pragma unroll
    for (int it = 0; it < 2; ++it) {
      int o = it * 4096 + t * 16;
      int row = o >> 6, colb = o & 63;
      *(bf16x8*)((char*)Als + o) =
          *(const bf16x8*)((const char*)Xb + (size_t)(m0 + row) * 768 + (size_t)k0 * 2 + colb);
      *(bf16x8*)((char*)Bls + o) =
          *(const bf16x8*)((const char*)Wt + (size_t)(n0 + row) * 768 + (size_t)k0 * 2 + colb);
    }
    __syncthreads();
    bf16x8 a[4], b[4];
#pragma unroll
    for (int m = 0; m < 4; ++m)
      a[m] = *(const bf16x8*)((const char*)Als + (wr * 64 + m * 16 + lo) * 64 + hi * 16);
#pragma unroll
    for (int n = 0; n < 4; ++n)
      b[n] = *(const bf16x8*)((const char*)Bls + (wc * 64 + n * 16 + lo) * 64 + hi * 16);
#pragma unroll
    for (int m = 0; m < 4; ++m)
#pragma unroll
      for (int n = 0; n < 4; ++n)
        acc[m][n] = __builtin_amdgcn_mfma_f32_16x16x32_bf16(a[m], b[n], acc[m][n], 0, 0, 0);
    __syncthreads();
  }
#pragma unroll
  for (int m = 0; m < 4; ++m)
#pragma unroll
    for (int n = 0; n < 4; ++n)
#pragma unroll
      for (int r = 0; r < 4; ++r) {
        int row = m0 + wr * 64 + m * 16 + 4 * hi + r;
        int col = n0 + wc * 64 + n * 16 + lo;
        unsigned short bv = f2bf(acc[m][n][r]);
        int bb = row >> 11, nn = row & 2047;
        int tsel = col / 384;
        int rr = col - tsel * 384;
        int hh = rr / 48, dd = rr - hh * 48;
        size_t bh = (size_t)(bb * 8 + hh);
        if (tsel == 0)
          Qo[bh * N_ * DK_ + (size_t)nn * DK_ + dd] = bv;
        else if (tsel == 1)
          Ko[bh * N_ * DK_ + (size_t)nn * DK_ + dd] = bv;
        else
          Vto[bh * 64 * N_ + (size_t)dd * N_ + nn] = bv;
      }
}

// ---------------- kernel 3: flash attention (swapped-operand 32x32) ----------------
// grid (16 qtiles, 64 bh), 256 threads = 4 independent waves, each wave = 32 q-rows
__global__ __launch_bounds__(256) void attn_kernel(
    const unsigned short* __restrict__ Q, const unsigned short* __restrict__ K,
    const unsigned short* __restrict__ Vt, unsigned short* __restrict__ AO) {
  int qt = blockIdx.x, bh = blockIdx.y;
  int lane = threadIdx.x & 63, w = threadIdx.x >> 6;
  int l31 = lane & 31, hi = lane >> 5;
  const unsigned short* Qb = Q + (size_t)bh * N_ * DK_;
  const unsigned short* Kb = K + (size_t)bh * N_ * DK_;
  const unsigned short* Vb = Vt + (size_t)bh * 64 * N_;
  int qrow0 = qt * 128 + w * 32;
  const float C1 = 0.02209708691207961f * 1.4426950408889634f;  // scale * log2(e)

  // Q fragments hoisted: B-operand, q = l31, k = ks*16 + hi*8 + j
  bf16x8 bq[3];
#pragma unroll
  for (int ks = 0; ks < 3; ++ks)
    bq[ks] = *(const bf16x8*)(Qb + (size_t)(qrow0 + l31) * DK_ + ks * 16 + hi * 8);

  f32x16 o0 = {}, o1 = {};       // O^T tiles: d = dt*32 + crow(reg,hi), q = l31
  float m2 = -1e30f, lsum = 0.f; // running max (log2-domain) and denom for q = l31

  for (int kv0 = 0; kv0 < N_; kv0 += 64) {
    // K A-frags: row = kv, k = ks*16 + hi*8 + j
    bf16x8 ak0[3], ak1[3];
#pragma unroll
    for (int ks = 0; ks < 3; ++ks) {
      ak0[ks] = *(const bf16x8*)(Kb + (size_t)(kv0 + l31) * DK_ + ks * 16 + hi * 8);
      ak1[ks] = *(const bf16x8*)(Kb + (size_t)(kv0 + 32 + l31) * DK_ + ks * 16 + hi * 8);
    }
    // V^T A-frags issued early (latency hidden under QK+softmax)
    bf16x8 av0[4], av1[4];
#pragma unroll
    for (int ks = 0; ks < 4; ++ks) {
      av0[ks] = *(const bf16x8*)(Vb + (size_t)l31 * N_ + kv0 + ks * 16 + hi * 8);
      av1[ks] = *(const bf16x8*)(Vb + (size_t)(32 + l31) * N_ + kv0 + ks * 16 + hi * 8);
    }
    // S^T[kv][q]: lane holds q = l31, kv = 32*ct + 4*hi + (r&3) + 8*(r>>2)
    f32x16 s0 = {}, s1 = {};
#pragma unroll
    for (int ks = 0; ks < 3; ++ks) {
      s0 = __builtin_amdgcn_mfma_f32_32x32x16_bf16(ak0[ks], bq[ks], s0, 0, 0, 0);
      s1 = __builtin_amdgcn_mfma_f32_32x32x16_bf16(ak1[ks], bq[ks], s1, 0, 0, 0);
    }
    // online softmax, fully in-register (row q = l31 split across lane and lane^32)
    float mr = fmaxf(tmax16(s0), tmax16(s1));
    mr = fmaxf(mr, __shfl_xor(mr, 32));
    float m2n = fmaxf(m2, mr * C1);
    float corr = __builtin_amdgcn_exp2f(m2 - m2n);
    m2 = m2n;
#pragma unroll
    for (int r = 0; r < 16; ++r) {
      s0[r] = __builtin_amdgcn_exp2f(__builtin_fmaf(s0[r], C1, -m2n));
      s1[r] = __builtin_amdgcn_exp2f(__builtin_fmaf(s1[r], C1, -m2n));
    }
    float rs = tsum16(s0) + tsum16(s1);
    rs += __shfl_xor(rs, 32);
    lsum = lsum * corr + rs;
#pragma unroll
    for (int r = 0; r < 16; ++r) { o0[r] *= corr; o1[r] *= corr; }
    // pack P to bf16 dwords: pd[ct][r2][d01] = kv pair (32ct + 8r2 + 4hi + 2*d01, +1)
    unsigned pd0[4][2], pd1[4][2];
#pragma unroll
    for (int r2 = 0; r2 < 4; ++r2) {
      pd0[r2][0] = cvt_pk_bf16(s0[4 * r2], s0[4 * r2 + 1]);
      pd0[r2][1] = cvt_pk_bf16(s0[4 * r2 + 2], s0[4 * r2 + 3]);
      pd1[r2][0] = cvt_pk_bf16(s1[4 * r2], s1[4 * r2 + 1]);
      pd1[r2][1] = cvt_pk_bf16(s1[4 * r2 + 2], s1[4 * r2 + 3]);
    }
    bool h1 = (hi != 0);
    // PV: B-frag for k-step ks needs kv = 8*(2ks+hi) + j  -> own/partner pd dwords
#pragma unroll
    for (int ks = 0; ks < 4; ++ks) {
      const int r2e = 2 * (ks & 1);
      unsigned a0, a1, b0, b1;  // a = pd[ct][r2e][*], b = pd[ct][r2e+1][*]
      if ((ks >> 1) == 0) {
        a0 = pd0[r2e][0]; a1 = pd0[r2e][1]; b0 = pd0[r2e + 1][0]; b1 = pd0[r2e + 1][1];
      } else {
        a0 = pd1[r2e][0]; a1 = pd1[r2e][1]; b0 = pd1[r2e + 1][0]; b1 = pd1[r2e + 1][1];
      }
      unsigned se0 = h1 ? a0 : b0;         // what the partner half needs
      unsigned se1 = h1 ? a1 : b1;
      unsigned rc0 = (unsigned)__shfl_xor((int)se0, 32);
      unsigned rc1 = (unsigned)__shfl_xor((int)se1, 32);
      unsigned ow0 = h1 ? b0 : a0;         // what this half keeps
      unsigned ow1 = h1 ? b1 : a1;
      u32x4 u;
      u[0] = h1 ? rc0 : ow0;
      u[1] = h1 ? rc1 : ow1;
      u[2] = h1 ? ow0 : rc0;
      u[3] = h1 ? ow1 : rc1;
      bf16x8 bp = __builtin_bit_cast(bf16x8, u);
      o0 = __builtin_amdgcn_mfma_f32_32x32x16_bf16(av0[ks], bp, o0, 0, 0, 0);
      o1 = __builtin_amdgcn_mfma_f32_32x32x16_bf16(av1[ks], bp, o1, 0, 0, 0);
    }
  }
  // epilogue: O[q][d] = o_dt[reg] / lsum ; d = dt*32 + 4hi + (r&3) + 8(r>>2)
  float il = __builtin_amdgcn_rcpf(lsum);
  int bb = bh >> 3, hh = bh & 7;
  unsigned short* rowp = AO + (size_t)(bb * N_ + qrow0 + l31) * D_ + hh * DK_;
#pragma unroll
  for (int r2 = 0; r2 < 4; ++r2) {
    ushort4 pk;
    pk.x = f2bf(o0[4 * r2] * il);
    pk.y = f2bf(o0[4 * r2 + 1] * il);
    pk.z = f2bf(o0[4 * r2 + 2] * il);
    pk.w = f2bf(o0[4 * r2 + 3] * il);
    *(ushort4*)(rowp + 8 * r2 + 4 * hi) = pk;
  }
#pragma unroll
  for (int r2 = 0; r2 < 2; ++r2) {   // dt=1 valid only for d_local < 16
    ushort4 pk;
    pk.x = f2bf(o1[4 * r2] * il);
    pk.y = f2bf(o1[4 * r2 + 1] * il);
    pk.z = f2bf(o1[4 * r2 + 2] * il);
    pk.w = f2bf(o1[4 * r2 + 3] * il);
    *(ushort4*)(rowp + 32 + 8 * r2 + 4 * hi) = pk;
  }
}

// ---------------- kernel 4: output projection + bias ----------------
__global__ __launch_bounds__(256) void gemm_out(
    const unsigned short* __restrict__ Ab, const unsigned short* __restrict__ Wt,
    const float* __restrict__ bias, float* __restrict__ Out) {
  __shared__ unsigned short Als[128 * 32];
  __shared__ unsigned short Bls[128 * 32];
  int t = threadIdx.x;
  int w = t >> 6, lane = t & 63, lo = lane & 15, hi = lane >> 4;
  int wr = w >> 1, wc = w & 1;
  int m0 = blockIdx.y * 128, n0 = blockIdx.x * 128;
  f32x4 acc[4][4] = {};
  for (int k0 = 0; k0 < D_; k0 += 32) {
#pragma unroll
    for (int it = 0; it < 2; ++it) {
      int o = it * 4096 + t * 16;
      int row = o >> 6, colb = o & 63;
      *(bf16x8*)((char*)Als + o) =
          *(const bf16x8*)((const char*)Ab + (size_t)(m0 + row) * 768 + (size_t)k0 * 2 + colb);
      *(bf16x8*)((char*)Bls + o) =
          *(const bf16x8*)((const char*)Wt + (size_t)(n0 + row) * 768 + (size_t)k0 * 2 + colb);
    }
    __syncthreads();
    bf16x8 a[4], b[4];
#pragma unroll
    for (int m = 0; m < 4; ++m)
      a[m] = *(const bf16x8*)((const char*)Als + (wr * 64 + m * 16 + lo) * 64 + hi * 16);
#pragma unroll
    for (int n = 0; n < 4; ++n)
      b[n] = *(const bf16x8*)((const char*)Bls + (wc * 64 + n * 16 + lo) * 64 + hi * 16);
#pragma unroll
    for (int m = 0; m < 4; ++m)
#pragma unroll
      for (int n = 0; n < 4; ++n)
        acc[m][n] = __builtin_amdgcn_mfma_f32_16x16x32_bf16(a[m], b[n], acc[m][n], 0, 0, 0);
    __syncthreads();
  }
  float bvals[4];
#pragma unroll
  for (int n = 0; n < 4; ++n) bvals[n] = bias[n0 + wc * 64 + n * 16 + lo];
#pragma unroll
  for (int m = 0; m < 4; ++m)
#pragma unroll
    for (int n = 0; n < 4; ++n)
#pragma unroll
      for (int r = 0; r < 4; ++r) {
        int row = m0 + wr * 64 + m * 16 + 4 * hi + r;
        int col = n0 + wc * 64 + n * 16 + lo;
        Out[(size_t)row * D_ + col] = acc[m][n][r] + bvals[n];
      }
}

extern "C" void kernel_launch(void* const* d_in, const int* in_sizes, int n_in,
                              void* d_out, int out_size, void* d_ws, size_t ws_size,
                              hipStream_t stream) {
  const float* x    = (const float*)d_in[0];
  const float* Wqkv = (const float*)d_in[1];
  const float* Wo   = (const float*)d_in[2];
  const float* bo   = (const float*)d_in[3];
  float* out = (float*)d_out;
  char* ws = (char*)d_ws;

  // workspace layout (bytes)
  unsigned short* xb  = (unsigned short*)(ws);               // 12,582,912
  unsigned short* WtQ = (unsigned short*)(ws + 12582912);    //    884,736
  unsigned short* WtO = (unsigned short*)(ws + 13467648);    //    294,912
  unsigned short* Qp  = (unsigned short*)(ws + 13762560);    // 12,582,912  [bh][2048][48]
  unsigned short* Kp  = (unsigned short*)(ws + 26345472);    // 12,582,912  [bh][2048][48]
  unsigned short* Vt  = (unsigned short*)(ws + 38928384);    // 16,777,216  [bh][64][2048]
  unsigned short* AO  = (unsigned short*)(ws + 55705600);    // 12,582,912
  const size_t WS_NEED = 68288512;
  if (ws_size < WS_NEED) return;

  cast_kernel<<<8448, 256, 0, stream>>>(x, Wqkv, Wo, xb, WtQ, WtO);
  gemm_qkv<<<dim3(9, 128), 256, 0, stream>>>(xb, WtQ, Qp, Kp, Vt);
  attn_kernel<<<dim3(16, 64), 256, 0, stream>>>(Qp, Kp, Vt, AO);
  gemm_out<<<dim3(3, 128), 256, 0, stream>>>(AO, WtO, bo, out);
}